// Round 3
// baseline (8672.352 us; speedup 1.0000x reference)
//
#include <hip/hip_runtime.h>

#define NSEG 63

typedef float    f32x4  __attribute__((ext_vector_type(4)));
typedef float    f32x2  __attribute__((ext_vector_type(2)));
typedef _Float16 half8  __attribute__((ext_vector_type(8)));
typedef _Float16 half4v __attribute__((ext_vector_type(4)));
typedef _Float16 half2v __attribute__((ext_vector_type(2)));

#define W2_ELEMS 524288
#define W1_ELEMS 16384
// ws layout (as _Float16*):
//   [0, 524288)          W2 hi frags  [kt][np=i*128+h][kk]
//   [524288, 1048576)    W2 lo frags
//   [1048576, +16384)    W1 hi frags  [kt][n][kk]
//   [1064960, +16384)    W1 lo frags
//   then float b2p[4096] (permuted np = i*128+h)
#define W1H_OFF (2*W2_ELEMS)
#define W1L_OFF (W1H_OFF + W1_ELEMS)
#define B2_OFF  (W1L_OFF + W1_ELEMS)

__device__ __forceinline__ float fast_tanh(float x){
  float e = __builtin_amdgcn_exp2f(x * 2.885390081777927f); // 2*log2(e)
  float r = __builtin_amdgcn_rcpf(e + 1.0f);
  return fmaf(-2.0f, r, 1.0f);
}

__device__ __forceinline__ f32x4 sp4(float v){ f32x4 o = {v,v,v,v}; return o; }

__global__ __launch_bounds__(256) void prep_kernel(const float* __restrict__ W1,
                                                   const float* __restrict__ W2,
                                                   const float* __restrict__ b2,
                                                   _Float16* __restrict__ ws){
  int idx = blockIdx.x*256 + threadIdx.x;
  if (idx < W2_ELEMS){
    int m = idx >> 12, col = idx & 4095;       // W2[m][col], col = h*32+i
    int h = col >> 5,  i = col & 31;
    int kt = m >> 5,   kk = m & 31;
    int np = i*128 + h;
    float w = W2[idx];
    _Float16 hi = (_Float16)w;
    _Float16 lo = (_Float16)(w - (float)hi);
    int pos = (kt*4096 + np)*32 + kk;
    ws[pos] = hi;
    ws[W2_ELEMS + pos] = lo;
  } else if (idx < W2_ELEMS + W1_ELEMS){
    int j = idx - W2_ELEMS;
    int m = j >> 7, n = j & 127;               // W1[m][n]
    float w = W1[j];
    _Float16 hi = (_Float16)w;
    _Float16 lo = (_Float16)(w - (float)hi);
    int pos = ((m>>5)*128 + n)*32 + (m&31);
    ws[W1H_OFF + pos] = hi;
    ws[W1L_OFF + pos] = lo;
  } else if (idx < W2_ELEMS + W1_ELEMS + 4096){
    int j = idx - (W2_ELEMS + W1_ELEMS);       // b2[h*32+i]
    float* b2p = (float*)(ws + B2_OFF);
    b2p[(j & 31)*128 + (j >> 5)] = b2[j];
  }
}

__global__ __launch_bounds__(1024, 4) void cde_kernel(
    const float* __restrict__ coeffs,
    const float* __restrict__ W_init, const float* __restrict__ b_init,
    const float* __restrict__ b1,
    const float* __restrict__ W_ro,  const float* __restrict__ b_ro,
    const float* __restrict__ We1,   const float* __restrict__ be1,
    const float* __restrict__ We2,   const float* __restrict__ be2,
    const _Float16* __restrict__ wsw,
    float* __restrict__ out)
{
  __shared__ __align__(16) float zb[16][128];       // z base (fp32 state)
  __shared__ __align__(16) float zacc[16][128];     // RK4 accumulator / evolve tmp
  __shared__ __align__(16) float dzs[2][16][128];   // partial k from each i-group
  __shared__ __align__(16) _Float16 Zs[16][136];    // stage-z hi (A of GEMM1)
  __shared__ __align__(16) _Float16 Zl[16][136];    // stage-z lo
  __shared__ __align__(16) _Float16 Hs[16][136];    // H hi (A of GEMM2)
  __shared__ __align__(16) _Float16 Hl[16][136];    // H lo
  __shared__ __align__(16) float dXT[3][32][16];    // dX variants, [var][i][b_local]
  __shared__ __align__(16) float ylds[16][32];      // evolve stage y
  __shared__ __align__(16) float b2L[4096];         // permuted b2

  const int tid  = threadIdx.x;
  const int wave = tid >> 6;          // 0..15
  const int lane = tid & 63;
  const int q    = lane >> 4;
  const int ln16 = lane & 15;
  const int row4 = q * 4;
  const int bg   = blockIdx.x * 16;
  const int grp  = wave >> 3;         // i-group 0/1
  const int ig0  = grp * 16;          // i range [ig0, ig0+16)

  // ---- stage b2p into LDS (coalesced) ----
  {
    const float* b2p = (const float*)(wsw + B2_OFF);
    #pragma unroll
    for (int j = 0; j < 4; ++j) b2L[tid + j*1024] = b2p[tid + j*1024];
  }
  // ---- stage X0 = a[:,0] into dXT[0][i][r] ----
  if (tid < 512){
    int r = tid >> 5, i = tid & 31;
    dXT[0][i][r] = coeffs[(size_t)(bg + r)*(NSEG*128) + i];
  }
  __syncthreads();

  // ---- z0 = X0 @ W_init + b_init (fp32), then hi/lo split ----
  if (tid < 512){
    int r = tid >> 5, h0 = (tid & 31) * 4;
    f32x4 acc = *(const f32x4*)&b_init[h0];
    #pragma unroll 8
    for (int i = 0; i < 32; ++i){
      float x = dXT[0][i][r];
      f32x4 w = *(const f32x4*)&W_init[i*128 + h0];
      acc += sp4(x) * w;
    }
    *(f32x4*)&zb[r][h0] = acc;
    half4v zh, zl;
    #pragma unroll
    for (int k = 0; k < 4; ++k){
      _Float16 hi = (_Float16)acc[k];
      zh[k] = hi; zl[k] = (_Float16)(acc[k] - (float)hi);
    }
    *(half4v*)&Zs[r][h0] = zh;
    *(half4v*)&Zl[r][h0] = zl;
  }

  // per-wave constants: n-tile shared by both i-groups
  const int n0 = (wave & 7) * 16;
  half8 w1h[4], w1l[4];
  {
    const half8* W1h8 = (const half8*)(wsw + W1H_OFF);
    const half8* W1l8 = (const half8*)(wsw + W1L_OFF);
    #pragma unroll
    for (int kt = 0; kt < 4; ++kt){
      int fi = (kt*128 + n0 + ln16)*4 + q;
      w1h[kt] = W1h8[fi];
      w1l[kt] = W1l8[fi];
    }
  }
  const float b1v = b1[n0 + ln16];
  const half8* Bh8 = (const half8*)wsw;                 // W2 hi plane
  const half8* Bl8 = (const half8*)(wsw + W2_ELEMS);    // W2 lo plane
  const int base8 = (n0 + ln16)*4 + q;                  // in half8 units
  __syncthreads();

  // ================= CDE RK4 scan =================
  for (int t = 0; t < NSEG; ++t){
    // stage dX variants for this step (transposed [i][b])
    if (tid < 512){
      int r = tid >> 5, i = tid & 31;
      const float* base = coeffs + (size_t)(bg + r)*(NSEG*128) + (size_t)t*128;
      float bb = base[32+i], cc = base[64+i], dd = base[96+i];
      dXT[0][i][r] = bb;                          // fr=0
      dXT[1][i][r] = bb + cc + 0.75f*dd;          // fr=0.5
      float d4;
      if (t < NSEG-1) d4 = base[128+32+i];        // next seg, fr=0
      else            d4 = bb + 2.0f*cc + 3.0f*dd;// seg 62, fr=1
      dXT[2][i][r] = d4;
    }
    __syncthreads();

    #pragma unroll 1
    for (int s = 0; s < 4; ++s){
      // ---- GEMM1 on waves 0-7: H = relu(Z @ W1 + b1), split-fp16 ----
      if (wave < 8){
        half8 a1h[4], a1l[4];
        #pragma unroll
        for (int kt = 0; kt < 4; ++kt){
          a1h[kt] = *(const half8*)&Zs[ln16][kt*32 + q*8];
          a1l[kt] = *(const half8*)&Zl[ln16][kt*32 + q*8];
        }
        f32x4 u0 = sp4(b1v), u1 = sp4(0.0f), u2 = sp4(0.0f);
        #pragma unroll
        for (int kt = 0; kt < 4; ++kt){
          u0 = __builtin_amdgcn_mfma_f32_16x16x32_f16(a1h[kt], w1h[kt], u0, 0, 0, 0);
          u1 = __builtin_amdgcn_mfma_f32_16x16x32_f16(a1l[kt], w1h[kt], u1, 0, 0, 0);
          u2 = __builtin_amdgcn_mfma_f32_16x16x32_f16(a1h[kt], w1l[kt], u2, 0, 0, 0);
        }
        #pragma unroll
        for (int r = 0; r < 4; ++r){
          float hv = u0[r] + u1[r] + u2[r];
          hv = hv > 0.0f ? hv : 0.0f;
          _Float16 hi = (_Float16)hv;
          Hs[row4 + r][n0 + ln16] = hi;
          Hl[row4 + r][n0 + ln16] = (_Float16)(hv - (float)hi);
        }
      }
      __syncthreads();

      // ---- GEMM2 + tanh + dX contraction: wave covers its 16 i's ----
      half8 a2h[4], a2l[4];
      #pragma unroll
      for (int kt = 0; kt < 4; ++kt){
        a2h[kt] = *(const half8*)&Hs[ln16][kt*32 + q*8];
        a2l[kt] = *(const half8*)&Hl[ln16][kt*32 + q*8];
      }
      const int v = (s == 0) ? 0 : ((s == 3) ? 2 : 1);
      f32x4 dzacc = sp4(0.0f);
      #pragma unroll 4
      for (int i = ig0; i < ig0 + 16; ++i){
        half8 bh0 = Bh8[base8 +             i*512];
        half8 bh1 = Bh8[base8 +   16384 +   i*512];
        half8 bh2 = Bh8[base8 + 2*16384 +   i*512];
        half8 bh3 = Bh8[base8 + 3*16384 +   i*512];
        half8 bl0 = Bl8[base8 +             i*512];
        half8 bl1 = Bl8[base8 +   16384 +   i*512];
        half8 bl2 = Bl8[base8 + 2*16384 +   i*512];
        half8 bl3 = Bl8[base8 + 3*16384 +   i*512];
        float b2v = b2L[i*128 + n0 + ln16];
        f32x4 u0 = sp4(b2v), u1 = sp4(0.0f), u2 = sp4(0.0f);
        u0 = __builtin_amdgcn_mfma_f32_16x16x32_f16(a2h[0], bh0, u0, 0, 0, 0);
        u1 = __builtin_amdgcn_mfma_f32_16x16x32_f16(a2l[0], bh0, u1, 0, 0, 0);
        u2 = __builtin_amdgcn_mfma_f32_16x16x32_f16(a2h[0], bl0, u2, 0, 0, 0);
        u0 = __builtin_amdgcn_mfma_f32_16x16x32_f16(a2h[1], bh1, u0, 0, 0, 0);
        u1 = __builtin_amdgcn_mfma_f32_16x16x32_f16(a2l[1], bh1, u1, 0, 0, 0);
        u2 = __builtin_amdgcn_mfma_f32_16x16x32_f16(a2h[1], bl1, u2, 0, 0, 0);
        u0 = __builtin_amdgcn_mfma_f32_16x16x32_f16(a2h[2], bh2, u0, 0, 0, 0);
        u1 = __builtin_amdgcn_mfma_f32_16x16x32_f16(a2l[2], bh2, u1, 0, 0, 0);
        u2 = __builtin_amdgcn_mfma_f32_16x16x32_f16(a2h[2], bl2, u2, 0, 0, 0);
        u0 = __builtin_amdgcn_mfma_f32_16x16x32_f16(a2h[3], bh3, u0, 0, 0, 0);
        u1 = __builtin_amdgcn_mfma_f32_16x16x32_f16(a2l[3], bh3, u1, 0, 0, 0);
        u2 = __builtin_amdgcn_mfma_f32_16x16x32_f16(a2h[3], bl3, u2, 0, 0, 0);
        f32x4 dxv = *(const f32x4*)&dXT[v][i][row4];
        #pragma unroll
        for (int r = 0; r < 4; ++r)
          dzacc[r] = fmaf(fast_tanh(u0[r] + u1[r] + u2[r]), dxv[r], dzacc[r]);
      }
      #pragma unroll
      for (int r = 0; r < 4; ++r)
        dzs[grp][row4 + r][n0 + ln16] = dzacc[r];
      __syncthreads();

      // ---- RK4 elementwise update (fp32 state), all 1024 threads ----
      {
        int r = tid >> 6, h0 = (tid & 63) * 2;
        f32x2 dz2;
        dz2.x = dzs[0][r][h0]   + dzs[1][r][h0];
        dz2.y = dzs[0][r][h0+1] + dzs[1][r][h0+1];
        f32x2 zb2 = *(const f32x2*)&zb[r][h0];
        f32x2 za;
        if (s == 0) za = dz2;
        else {
          float w = (s == 3) ? 1.0f : 2.0f;
          f32x2 zp = *(const f32x2*)&zacc[r][h0];
          za.x = zp.x + w*dz2.x; za.y = zp.y + w*dz2.y;
        }
        *(f32x2*)&zacc[r][h0] = za;
        f32x2 zs2;
        if (s == 3){
          zb2.x += za.x*(1.0f/6.0f); zb2.y += za.y*(1.0f/6.0f);
          *(f32x2*)&zb[r][h0] = zb2;
          zs2 = zb2;
        } else if (s == 2){ zs2.x = zb2.x + dz2.x; zs2.y = zb2.y + dz2.y; }
        else              { zs2.x = zb2.x + 0.5f*dz2.x; zs2.y = zb2.y + 0.5f*dz2.y; }
        half2v zh, zl;
        #pragma unroll
        for (int k = 0; k < 2; ++k){
          _Float16 hi = (_Float16)zs2[k];
          zh[k] = hi; zl[k] = (_Float16)(zs2[k] - (float)hi);
        }
        *(half2v*)&Zs[r][h0] = zh;
        *(half2v*)&Zl[r][h0] = zl;
      }
      __syncthreads();
    }
  }

  // ================= readout + evolve head (tid<512, fp32 scalar) =================
  const int r = tid >> 5, c = tid & 31;
  float yb = 0.0f, yac = 0.0f;
  if (tid < 512){
    float yv = b_ro[c];
    #pragma unroll 8
    for (int h = 0; h < 128; ++h)
      yv = fmaf(zb[r][h], W_ro[h*32 + c], yv);
    ylds[r][c] = yv;
    yb = yv;
  }
  __syncthreads();

  for (int st = 0; st < 10; ++st){
    #pragma unroll 1
    for (int s = 0; s < 4; ++s){
      if (tid < 512){
        int rr = tid >> 5, m0 = (tid & 31) * 4;
        f32x4 acc = *(const f32x4*)&be1[m0];
        #pragma unroll 4
        for (int i = 0; i < 32; ++i){
          float x = ylds[rr][i];
          acc += sp4(x) * (*(const f32x4*)&We1[i*128 + m0]);
        }
        f32x4 tt;
        tt.x = fast_tanh(acc.x); tt.y = fast_tanh(acc.y);
        tt.z = fast_tanh(acc.z); tt.w = fast_tanh(acc.w);
        *(f32x4*)&zacc[rr][m0] = tt;
      }
      __syncthreads();
      if (tid < 512){
        float kv = be2[c];
        #pragma unroll 8
        for (int m = 0; m < 128; ++m)
          kv = fmaf(zacc[r][m], We2[m*32 + c], kv);
        float ysn;
        if      (s == 0){ yac = kv;        ysn = yb + 0.25f*kv; }
        else if (s == 1){ yac += 2.0f*kv;  ysn = yb + 0.25f*kv; }
        else if (s == 2){ yac += 2.0f*kv;  ysn = yb + 0.5f*kv;  }
        else            { yac += kv;       yb  = yb + yac*(1.0f/12.0f); ysn = yb; }
        ylds[r][c] = ysn;
      }
      __syncthreads();
    }
  }
  if (tid < 512)
    out[(size_t)(bg + r)*32 + c] = yb;
}

extern "C" void kernel_launch(void* const* d_in, const int* in_sizes, int n_in,
                              void* d_out, int out_size, void* d_ws, size_t ws_size,
                              hipStream_t stream){
  const float* coeffs = (const float*)d_in[0];
  const float* W_init = (const float*)d_in[1];
  const float* b_init = (const float*)d_in[2];
  const float* W1     = (const float*)d_in[3];
  const float* b1     = (const float*)d_in[4];
  const float* W2     = (const float*)d_in[5];
  const float* b2     = (const float*)d_in[6];
  const float* W_ro   = (const float*)d_in[7];
  const float* b_ro   = (const float*)d_in[8];
  const float* We1    = (const float*)d_in[9];
  const float* be1    = (const float*)d_in[10];
  const float* We2    = (const float*)d_in[11];
  const float* be2    = (const float*)d_in[12];
  _Float16* ws        = (_Float16*)d_ws;

  prep_kernel<<<2128, 256, 0, stream>>>(W1, W2, b2, ws);
  cde_kernel<<<128, 1024, 0, stream>>>(coeffs, W_init, b_init, b1, W_ro, b_ro,
                                       We1, be1, We2, be2, ws, (float*)d_out);
}

// Round 4
// 8123.821 us; speedup vs baseline: 1.0675x; 1.0675x over previous
//
#include <hip/hip_runtime.h>

#define NSEG 63

typedef float    f32x4  __attribute__((ext_vector_type(4)));
typedef _Float16 half8  __attribute__((ext_vector_type(8)));
typedef _Float16 half4v __attribute__((ext_vector_type(4)));

#define W2_ELEMS 524288
#define W1_ELEMS 16384
// ws layout (as _Float16*):
//   [0, 524288)          W2 hi frags  [kt][np=i*128+h][kk]
//   [524288, 1048576)    W2 lo frags
//   [1048576, +16384)    W1 hi frags  [kt][n][kk]
//   [1064960, +16384)    W1 lo frags
//   then float b2p[4096] (permuted np = i*128+h)
#define W1H_OFF (2*W2_ELEMS)
#define W1L_OFF (W1H_OFF + W1_ELEMS)
#define B2_OFF  (W1L_OFF + W1_ELEMS)

__device__ __forceinline__ float fast_tanh(float x){
  float e = __builtin_amdgcn_exp2f(x * 2.885390081777927f); // 2*log2(e)
  float r = __builtin_amdgcn_rcpf(e + 1.0f);
  return fmaf(-2.0f, r, 1.0f);
}

__device__ __forceinline__ f32x4 sp4(float v){ f32x4 o = {v,v,v,v}; return o; }

__global__ __launch_bounds__(256) void prep_kernel(const float* __restrict__ W1,
                                                   const float* __restrict__ W2,
                                                   const float* __restrict__ b2,
                                                   _Float16* __restrict__ ws){
  int idx = blockIdx.x*256 + threadIdx.x;
  if (idx < W2_ELEMS){
    int m = idx >> 12, col = idx & 4095;       // W2[m][col], col = h*32+i
    int h = col >> 5,  i = col & 31;
    int kt = m >> 5,   kk = m & 31;
    int np = i*128 + h;
    float w = W2[idx];
    _Float16 hi = (_Float16)w;
    _Float16 lo = (_Float16)(w - (float)hi);
    int pos = (kt*4096 + np)*32 + kk;
    ws[pos] = hi;
    ws[W2_ELEMS + pos] = lo;
  } else if (idx < W2_ELEMS + W1_ELEMS){
    int j = idx - W2_ELEMS;
    int m = j >> 7, n = j & 127;               // W1[m][n]
    float w = W1[j];
    _Float16 hi = (_Float16)w;
    _Float16 lo = (_Float16)(w - (float)hi);
    int pos = ((m>>5)*128 + n)*32 + (m&31);
    ws[W1H_OFF + pos] = hi;
    ws[W1L_OFF + pos] = lo;
  } else if (idx < W2_ELEMS + W1_ELEMS + 4096){
    int j = idx - (W2_ELEMS + W1_ELEMS);       // b2[h*32+i]
    float* b2p = (float*)(ws + B2_OFF);
    b2p[(j & 31)*128 + (j >> 5)] = b2[j];
  }
}

// 64 WGs x 512 threads x 32 batch rows. M=32 as two 16-row MFMA tiles.
// z-state in registers: lane (q,ln16) of wave w owns rows {q*4..+3, 16+q*4..+3},
// col n0+ln16 (its own MFMA C-fragment). 2 barriers per substep.
__global__ __launch_bounds__(512, 2) void cde_kernel(
    const float* __restrict__ coeffs,
    const float* __restrict__ W_init, const float* __restrict__ b_init,
    const float* __restrict__ b1,
    const float* __restrict__ W_ro,  const float* __restrict__ b_ro,
    const float* __restrict__ We1,   const float* __restrict__ be1,
    const float* __restrict__ We2,   const float* __restrict__ be2,
    const _Float16* __restrict__ wsw,
    float* __restrict__ out)
{
  __shared__ __align__(16) _Float16 Zs[32][136];  // stage-z hi (A of GEMM1)
  __shared__ __align__(16) _Float16 Zl[32][136];  // stage-z lo
  __shared__ __align__(16) _Float16 Hs[32][136];  // H hi (A of GEMM2)
  __shared__ __align__(16) _Float16 Hl[32][136];  // H lo
  __shared__ __align__(16) float dXT[3][32][32];  // dX variants [var][i][row]
  __shared__ __align__(16) float zfb[32][128];    // z0 init + final readout
  __shared__ __align__(16) float ylds[32][32];    // evolve stage y
  __shared__ __align__(16) float b2L[4096];       // permuted b2; reused as evolve tmp

  const int tid  = threadIdx.x;
  const int wave = tid >> 6;          // 0..7
  const int lane = tid & 63;
  const int q    = lane >> 4;
  const int ln16 = lane & 15;
  const int row4 = q * 4;
  const int bg   = blockIdx.x * 32;
  const int n0   = wave * 16;

  // ---- stage b2p into LDS ----
  {
    const float* b2p = (const float*)(wsw + B2_OFF);
    #pragma unroll
    for (int j = 0; j < 8; ++j) b2L[tid + j*512] = b2p[tid + j*512];
  }
  // ---- stage X0 = a[:,0] into dXT[0][i][r] ----
  #pragma unroll
  for (int j = 0; j < 2; ++j){
    int idx = tid + j*512;
    int r = idx >> 5, i = idx & 31;
    dXT[0][i][r] = coeffs[(size_t)(bg + r)*(NSEG*128) + i];
  }
  __syncthreads();

  // ---- z0 = X0 @ W_init + b_init (fp32) -> zfb + Zs/Zl ----
  #pragma unroll
  for (int j = 0; j < 2; ++j){
    int idx = tid + j*512;
    int r = idx >> 5, h0 = (idx & 31) * 4;
    f32x4 acc = *(const f32x4*)&b_init[h0];
    #pragma unroll 8
    for (int i = 0; i < 32; ++i)
      acc += sp4(dXT[0][i][r]) * (*(const f32x4*)&W_init[i*128 + h0]);
    *(f32x4*)&zfb[r][h0] = acc;
    half4v zh, zl;
    #pragma unroll
    for (int k = 0; k < 4; ++k){
      _Float16 hi = (_Float16)acc[k];
      zh[k] = hi; zl[k] = (_Float16)(acc[k] - (float)hi);
    }
    *(half4v*)&Zs[r][h0] = zh;
    *(half4v*)&Zl[r][h0] = zl;
  }

  // per-wave W1 fragments (persist in regs)
  half8 w1h[4], w1l[4];
  {
    const half8* W1h8 = (const half8*)(wsw + W1H_OFF);
    const half8* W1l8 = (const half8*)(wsw + W1L_OFF);
    #pragma unroll
    for (int kt = 0; kt < 4; ++kt){
      int fi = (kt*128 + n0 + ln16)*4 + q;
      w1h[kt] = W1h8[fi];
      w1l[kt] = W1l8[fi];
    }
  }
  const float b1v = b1[n0 + ln16];
  const half8* Bh8 = (const half8*)wsw;
  const half8* Bl8 = (const half8*)(wsw + W2_ELEMS);
  const int base8 = (n0 + ln16)*4 + q;
  __syncthreads();

  // ---- register z-state for owned fragment ----
  f32x4 zbA, zbB, zaA = sp4(0.0f), zaB = sp4(0.0f);
  #pragma unroll
  for (int k = 0; k < 4; ++k){
    zbA[k] = zfb[row4 + k][n0 + ln16];
    zbB[k] = zfb[16 + row4 + k][n0 + ln16];
  }

  // ================= CDE RK4 scan =================
  for (int t = 0; t < NSEG; ++t){
    // stage dX variants (runs alongside phase A of s=0; readers are in phase B)
    #pragma unroll
    for (int j = 0; j < 2; ++j){
      int idx = tid + j*512;
      int r = idx >> 5, i = idx & 31;
      const float* base = coeffs + (size_t)(bg + r)*(NSEG*128) + (size_t)t*128;
      float bb = base[32+i], cc = base[64+i], dd = base[96+i];
      dXT[0][i][r] = bb;
      dXT[1][i][r] = bb + cc + 0.75f*dd;
      float d4;
      if (t < NSEG-1) d4 = base[128+32+i];
      else            d4 = bb + 2.0f*cc + 3.0f*dd;
      dXT[2][i][r] = d4;
    }

    #pragma unroll 1
    for (int s = 0; s < 4; ++s){
      // ---- Phase A: GEMM1 both M-tiles: H = relu(Z @ W1 + b1) ----
      {
        half8 a1hA[4], a1lA[4], a1hB[4], a1lB[4];
        #pragma unroll
        for (int kt = 0; kt < 4; ++kt){
          a1hA[kt] = *(const half8*)&Zs[ln16][kt*32 + q*8];
          a1lA[kt] = *(const half8*)&Zl[ln16][kt*32 + q*8];
          a1hB[kt] = *(const half8*)&Zs[16 + ln16][kt*32 + q*8];
          a1lB[kt] = *(const half8*)&Zl[16 + ln16][kt*32 + q*8];
        }
        f32x4 u0A = sp4(b1v), u1A = sp4(0.0f), u2A = sp4(0.0f);
        f32x4 u0B = sp4(b1v), u1B = sp4(0.0f), u2B = sp4(0.0f);
        #pragma unroll
        for (int kt = 0; kt < 4; ++kt){
          u0A = __builtin_amdgcn_mfma_f32_16x16x32_f16(a1hA[kt], w1h[kt], u0A, 0, 0, 0);
          u1A = __builtin_amdgcn_mfma_f32_16x16x32_f16(a1lA[kt], w1h[kt], u1A, 0, 0, 0);
          u2A = __builtin_amdgcn_mfma_f32_16x16x32_f16(a1hA[kt], w1l[kt], u2A, 0, 0, 0);
          u0B = __builtin_amdgcn_mfma_f32_16x16x32_f16(a1hB[kt], w1h[kt], u0B, 0, 0, 0);
          u1B = __builtin_amdgcn_mfma_f32_16x16x32_f16(a1lB[kt], w1h[kt], u1B, 0, 0, 0);
          u2B = __builtin_amdgcn_mfma_f32_16x16x32_f16(a1hB[kt], w1l[kt], u2B, 0, 0, 0);
        }
        #pragma unroll
        for (int r = 0; r < 4; ++r){
          float hvA = u0A[r] + u1A[r] + u2A[r];
          hvA = hvA > 0.0f ? hvA : 0.0f;
          _Float16 hiA = (_Float16)hvA;
          Hs[row4 + r][n0 + ln16] = hiA;
          Hl[row4 + r][n0 + ln16] = (_Float16)(hvA - (float)hiA);
          float hvB = u0B[r] + u1B[r] + u2B[r];
          hvB = hvB > 0.0f ? hvB : 0.0f;
          _Float16 hiB = (_Float16)hvB;
          Hs[16 + row4 + r][n0 + ln16] = hiB;
          Hl[16 + row4 + r][n0 + ln16] = (_Float16)(hvB - (float)hiB);
        }
      }
      __syncthreads();

      // ---- Phase B: GEMM2 + tanh + dX contraction + in-register RK4 ----
      {
        half8 a2hA[4], a2lA[4], a2hB[4], a2lB[4];
        #pragma unroll
        for (int kt = 0; kt < 4; ++kt){
          a2hA[kt] = *(const half8*)&Hs[ln16][kt*32 + q*8];
          a2lA[kt] = *(const half8*)&Hl[ln16][kt*32 + q*8];
          a2hB[kt] = *(const half8*)&Hs[16 + ln16][kt*32 + q*8];
          a2lB[kt] = *(const half8*)&Hl[16 + ln16][kt*32 + q*8];
        }
        const int v = (s == 0) ? 0 : ((s == 3) ? 2 : 1);
        f32x4 dzA = sp4(0.0f), dzB = sp4(0.0f);
        #pragma unroll 2
        for (int i = 0; i < 32; ++i){
          half8 bh0 = Bh8[base8 +             i*512];
          half8 bh1 = Bh8[base8 +   16384 +   i*512];
          half8 bh2 = Bh8[base8 + 2*16384 +   i*512];
          half8 bh3 = Bh8[base8 + 3*16384 +   i*512];
          half8 bl0 = Bl8[base8 +             i*512];
          half8 bl1 = Bl8[base8 +   16384 +   i*512];
          half8 bl2 = Bl8[base8 + 2*16384 +   i*512];
          half8 bl3 = Bl8[base8 + 3*16384 +   i*512];
          float b2v = b2L[i*128 + n0 + ln16];
          f32x4 u0A = sp4(b2v), u1A = sp4(0.0f), u2A = sp4(0.0f);
          f32x4 u0B = sp4(b2v), u1B = sp4(0.0f), u2B = sp4(0.0f);
          u0A = __builtin_amdgcn_mfma_f32_16x16x32_f16(a2hA[0], bh0, u0A, 0, 0, 0);
          u1A = __builtin_amdgcn_mfma_f32_16x16x32_f16(a2lA[0], bh0, u1A, 0, 0, 0);
          u2A = __builtin_amdgcn_mfma_f32_16x16x32_f16(a2hA[0], bl0, u2A, 0, 0, 0);
          u0B = __builtin_amdgcn_mfma_f32_16x16x32_f16(a2hB[0], bh0, u0B, 0, 0, 0);
          u1B = __builtin_amdgcn_mfma_f32_16x16x32_f16(a2lB[0], bh0, u1B, 0, 0, 0);
          u2B = __builtin_amdgcn_mfma_f32_16x16x32_f16(a2hB[0], bl0, u2B, 0, 0, 0);
          u0A = __builtin_amdgcn_mfma_f32_16x16x32_f16(a2hA[1], bh1, u0A, 0, 0, 0);
          u1A = __builtin_amdgcn_mfma_f32_16x16x32_f16(a2lA[1], bh1, u1A, 0, 0, 0);
          u2A = __builtin_amdgcn_mfma_f32_16x16x32_f16(a2hA[1], bl1, u2A, 0, 0, 0);
          u0B = __builtin_amdgcn_mfma_f32_16x16x32_f16(a2hB[1], bh1, u0B, 0, 0, 0);
          u1B = __builtin_amdgcn_mfma_f32_16x16x32_f16(a2lB[1], bh1, u1B, 0, 0, 0);
          u2B = __builtin_amdgcn_mfma_f32_16x16x32_f16(a2hB[1], bl1, u2B, 0, 0, 0);
          u0A = __builtin_amdgcn_mfma_f32_16x16x32_f16(a2hA[2], bh2, u0A, 0, 0, 0);
          u1A = __builtin_amdgcn_mfma_f32_16x16x32_f16(a2lA[2], bh2, u1A, 0, 0, 0);
          u2A = __builtin_amdgcn_mfma_f32_16x16x32_f16(a2hA[2], bl2, u2A, 0, 0, 0);
          u0B = __builtin_amdgcn_mfma_f32_16x16x32_f16(a2hB[2], bh2, u0B, 0, 0, 0);
          u1B = __builtin_amdgcn_mfma_f32_16x16x32_f16(a2lB[2], bh2, u1B, 0, 0, 0);
          u2B = __builtin_amdgcn_mfma_f32_16x16x32_f16(a2hB[2], bl2, u2B, 0, 0, 0);
          u0A = __builtin_amdgcn_mfma_f32_16x16x32_f16(a2hA[3], bh3, u0A, 0, 0, 0);
          u1A = __builtin_amdgcn_mfma_f32_16x16x32_f16(a2lA[3], bh3, u1A, 0, 0, 0);
          u2A = __builtin_amdgcn_mfma_f32_16x16x32_f16(a2hA[3], bl3, u2A, 0, 0, 0);
          u0B = __builtin_amdgcn_mfma_f32_16x16x32_f16(a2hB[3], bh3, u0B, 0, 0, 0);
          u1B = __builtin_amdgcn_mfma_f32_16x16x32_f16(a2lB[3], bh3, u1B, 0, 0, 0);
          u2B = __builtin_amdgcn_mfma_f32_16x16x32_f16(a2hB[3], bl3, u2B, 0, 0, 0);
          f32x4 dxvA = *(const f32x4*)&dXT[v][i][row4];
          f32x4 dxvB = *(const f32x4*)&dXT[v][i][16 + row4];
          #pragma unroll
          for (int r = 0; r < 4; ++r){
            dzA[r] = fmaf(fast_tanh(u0A[r] + u1A[r] + u2A[r]), dxvA[r], dzA[r]);
            dzB[r] = fmaf(fast_tanh(u0B[r] + u1B[r] + u2B[r]), dxvB[r], dzB[r]);
          }
        }

        // in-register RK4 update + Zs/Zl write for owned fragment
        const float wk = (s == 3) ? 1.0f : 2.0f;
        #pragma unroll
        for (int k = 0; k < 4; ++k){
          // tile A
          float za = (s == 0) ? dzA[k] : zaA[k] + wk*dzA[k];
          zaA[k] = za;
          float zs;
          if (s == 3){ zbA[k] += za*(1.0f/6.0f); zs = zbA[k]; }
          else if (s == 2) zs = zbA[k] + dzA[k];
          else             zs = zbA[k] + 0.5f*dzA[k];
          _Float16 hi = (_Float16)zs;
          Zs[row4 + k][n0 + ln16] = hi;
          Zl[row4 + k][n0 + ln16] = (_Float16)(zs - (float)hi);
          // tile B
          float zb2 = (s == 0) ? dzB[k] : zaB[k] + wk*dzB[k];
          zaB[k] = zb2;
          float zs2;
          if (s == 3){ zbB[k] += zb2*(1.0f/6.0f); zs2 = zbB[k]; }
          else if (s == 2) zs2 = zbB[k] + dzB[k];
          else             zs2 = zbB[k] + 0.5f*dzB[k];
          _Float16 hi2 = (_Float16)zs2;
          Zs[16 + row4 + k][n0 + ln16] = hi2;
          Zl[16 + row4 + k][n0 + ln16] = (_Float16)(zs2 - (float)hi2);
        }
      }
      __syncthreads();
    }
  }

  // ---- write final z back to zfb for readout ----
  #pragma unroll
  for (int k = 0; k < 4; ++k){
    zfb[row4 + k][n0 + ln16]      = zbA[k];
    zfb[16 + row4 + k][n0 + ln16] = zbB[k];
  }
  __syncthreads();

  // ================= readout + evolve head (fp32) =================
  float yb[2], yac[2] = {0.0f, 0.0f};
  #pragma unroll
  for (int j = 0; j < 2; ++j){
    int idx = tid + j*512;
    int r = idx >> 5, c = idx & 31;
    float yv = b_ro[c];
    #pragma unroll 8
    for (int h = 0; h < 128; ++h)
      yv = fmaf(zfb[r][h], W_ro[h*32 + c], yv);
    ylds[r][c] = yv;
    yb[j] = yv;
  }
  __syncthreads();

  for (int st = 0; st < 10; ++st){
    #pragma unroll 1
    for (int s = 0; s < 4; ++s){
      // tmp = tanh(ys @ We1 + be1) -> b2L (reused as [32][128])
      #pragma unroll
      for (int j = 0; j < 2; ++j){
        int idx = tid + j*512;
        int rr = idx >> 5, m0 = (idx & 31) * 4;
        f32x4 acc = *(const f32x4*)&be1[m0];
        #pragma unroll 4
        for (int i = 0; i < 32; ++i)
          acc += sp4(ylds[rr][i]) * (*(const f32x4*)&We1[i*128 + m0]);
        f32x4 tt;
        tt.x = fast_tanh(acc.x); tt.y = fast_tanh(acc.y);
        tt.z = fast_tanh(acc.z); tt.w = fast_tanh(acc.w);
        *(f32x4*)&b2L[rr*128 + m0] = tt;
      }
      __syncthreads();
      #pragma unroll
      for (int j = 0; j < 2; ++j){
        int idx = tid + j*512;
        int r = idx >> 5, c = idx & 31;
        float kv = be2[c];
        #pragma unroll 8
        for (int m = 0; m < 128; ++m)
          kv = fmaf(b2L[r*128 + m], We2[m*32 + c], kv);
        float ysn;
        if      (s == 0){ yac[j] = kv;        ysn = yb[j] + 0.25f*kv; }
        else if (s == 1){ yac[j] += 2.0f*kv;  ysn = yb[j] + 0.25f*kv; }
        else if (s == 2){ yac[j] += 2.0f*kv;  ysn = yb[j] + 0.5f*kv;  }
        else            { yac[j] += kv;       yb[j] += yac[j]*(1.0f/12.0f); ysn = yb[j]; }
        ylds[r][c] = ysn;
      }
      __syncthreads();
    }
  }
  #pragma unroll
  for (int j = 0; j < 2; ++j){
    int idx = tid + j*512;
    int r = idx >> 5, c = idx & 31;
    out[(size_t)(bg + r)*32 + c] = yb[j];
  }
}

extern "C" void kernel_launch(void* const* d_in, const int* in_sizes, int n_in,
                              void* d_out, int out_size, void* d_ws, size_t ws_size,
                              hipStream_t stream){
  const float* coeffs = (const float*)d_in[0];
  const float* W_init = (const float*)d_in[1];
  const float* b_init = (const float*)d_in[2];
  const float* W1     = (const float*)d_in[3];
  const float* b1     = (const float*)d_in[4];
  const float* W2     = (const float*)d_in[5];
  const float* b2     = (const float*)d_in[6];
  const float* W_ro   = (const float*)d_in[7];
  const float* b_ro   = (const float*)d_in[8];
  const float* We1    = (const float*)d_in[9];
  const float* be1    = (const float*)d_in[10];
  const float* We2    = (const float*)d_in[11];
  const float* be2    = (const float*)d_in[12];
  _Float16* ws        = (_Float16*)d_ws;

  prep_kernel<<<2128, 256, 0, stream>>>(W1, W2, b2, ws);
  cde_kernel<<<64, 512, 0, stream>>>(coeffs, W_init, b_init, b1, W_ro, b_ro,
                                     We1, be1, We2, be2, ws, (float*)d_out);
}

// Round 5
// 7240.436 us; speedup vs baseline: 1.1978x; 1.1220x over previous
//
#include <hip/hip_runtime.h>

#define NSEG 63

typedef float    f32x4  __attribute__((ext_vector_type(4)));
typedef _Float16 half8  __attribute__((ext_vector_type(8)));
typedef _Float16 half4v __attribute__((ext_vector_type(4)));

#define W2_ELEMS 524288
#define W1_ELEMS 16384
#define W1H_OFF (2*W2_ELEMS)
#define W1L_OFF (W1H_OFF + W1_ELEMS)
#define B2_OFF  (W1L_OFF + W1_ELEMS)

__device__ __forceinline__ float fast_tanh(float x){
  float e = __builtin_amdgcn_exp2f(x * 2.885390081777927f); // 2*log2(e)
  float r = __builtin_amdgcn_rcpf(e + 1.0f);
  return fmaf(-2.0f, r, 1.0f);
}

__device__ __forceinline__ f32x4 sp4(float v){ f32x4 o = {v,v,v,v}; return o; }

__global__ __launch_bounds__(256) void prep_kernel(const float* __restrict__ W1,
                                                   const float* __restrict__ W2,
                                                   const float* __restrict__ b2,
                                                   _Float16* __restrict__ ws){
  int idx = blockIdx.x*256 + threadIdx.x;
  if (idx < W2_ELEMS){
    int m = idx >> 12, col = idx & 4095;       // W2[m][col], col = h*32+i
    int h = col >> 5,  i = col & 31;
    int kt = m >> 5,   kk = m & 31;
    int np = i*128 + h;
    float w = W2[idx];
    _Float16 hi = (_Float16)w;
    _Float16 lo = (_Float16)(w - (float)hi);
    int pos = (kt*4096 + np)*32 + kk;
    ws[pos] = hi;
    ws[W2_ELEMS + pos] = lo;
  } else if (idx < W2_ELEMS + W1_ELEMS){
    int j = idx - W2_ELEMS;
    int m = j >> 7, n = j & 127;               // W1[m][n]
    float w = W1[j];
    _Float16 hi = (_Float16)w;
    _Float16 lo = (_Float16)(w - (float)hi);
    int pos = ((m>>5)*128 + n)*32 + (m&31);
    ws[W1H_OFF + pos] = hi;
    ws[W1L_OFF + pos] = lo;
  } else if (idx < W2_ELEMS + W1_ELEMS + 4096){
    int j = idx - (W2_ELEMS + W1_ELEMS);       // b2[h*32+i]
    float* b2p = (float*)(ws + B2_OFF);
    b2p[(j & 31)*128 + (j >> 5)] = b2[j];
  }
}

// 128 WGs x 512 threads x 16 rows. 1 M-tile per wave, register z-state,
// 2 barriers/substep, register double-buffered W2 B-fragments.
__global__ __launch_bounds__(512, 2) void cde_kernel(
    const float* __restrict__ coeffs,
    const float* __restrict__ W_init, const float* __restrict__ b_init,
    const float* __restrict__ b1,
    const float* __restrict__ W_ro,  const float* __restrict__ b_ro,
    const float* __restrict__ We1,   const float* __restrict__ be1,
    const float* __restrict__ We2,   const float* __restrict__ be2,
    const _Float16* __restrict__ wsw,
    float* __restrict__ out)
{
  __shared__ __align__(16) _Float16 Zs[16][136];  // stage-z hi (A of GEMM1)
  __shared__ __align__(16) _Float16 Zl[16][136];  // stage-z lo
  __shared__ __align__(16) _Float16 Hs[16][136];  // H hi (A of GEMM2)
  __shared__ __align__(16) _Float16 Hl[16][136];  // H lo
  __shared__ __align__(16) float dXT[3][32][16];  // dX variants [var][i][row]
  __shared__ __align__(16) float zfb[16][128];    // z0 init + final readout
  __shared__ __align__(16) float ylds[16][32];    // evolve stage y
  __shared__ __align__(16) float b2L[4096];       // permuted b2; reused as evolve tmp

  const int tid  = threadIdx.x;
  const int wave = tid >> 6;          // 0..7
  const int lane = tid & 63;
  const int q    = lane >> 4;
  const int ln16 = lane & 15;
  const int row4 = q * 4;
  const int bg   = blockIdx.x * 16;
  const int n0   = wave * 16;

  // ---- stage b2p into LDS ----
  {
    const float* b2p = (const float*)(wsw + B2_OFF);
    #pragma unroll
    for (int j = 0; j < 8; ++j) b2L[tid + j*512] = b2p[tid + j*512];
  }
  // ---- stage X0 = a[:,0] into dXT[0][i][r] ----
  {
    int r = tid >> 5, i = tid & 31;
    dXT[0][i][r] = coeffs[(size_t)(bg + r)*(NSEG*128) + i];
  }
  __syncthreads();

  // ---- z0 = X0 @ W_init + b_init (fp32) -> zfb + Zs/Zl ----
  {
    int r = tid >> 5, h0 = (tid & 31) * 4;
    f32x4 acc = *(const f32x4*)&b_init[h0];
    #pragma unroll 8
    for (int i = 0; i < 32; ++i)
      acc += sp4(dXT[0][i][r]) * (*(const f32x4*)&W_init[i*128 + h0]);
    *(f32x4*)&zfb[r][h0] = acc;
    half4v zh, zl;
    #pragma unroll
    for (int k = 0; k < 4; ++k){
      _Float16 hi = (_Float16)acc[k];
      zh[k] = hi; zl[k] = (_Float16)(acc[k] - (float)hi);
    }
    *(half4v*)&Zs[r][h0] = zh;
    *(half4v*)&Zl[r][h0] = zl;
  }

  // per-wave W1 fragments (persist in regs)
  half8 w1h[4], w1l[4];
  {
    const half8* W1h8 = (const half8*)(wsw + W1H_OFF);
    const half8* W1l8 = (const half8*)(wsw + W1L_OFF);
    #pragma unroll
    for (int kt = 0; kt < 4; ++kt){
      int fi = (kt*128 + n0 + ln16)*4 + q;
      w1h[kt] = W1h8[fi];
      w1l[kt] = W1l8[fi];
    }
  }
  const float b1v = b1[n0 + ln16];
  const half8* Bh8 = (const half8*)wsw;
  const half8* Bl8 = (const half8*)(wsw + W2_ELEMS);
  const int base8 = (n0 + ln16)*4 + q;
  __syncthreads();

  // ---- register z-state for owned fragment ----
  f32x4 zb, za = sp4(0.0f);
  #pragma unroll
  for (int k = 0; k < 4; ++k)
    zb[k] = zfb[row4 + k][n0 + ln16];

  // B-fragment loader: bf[0..3] = hi planes kt0..3, bf[4..7] = lo planes
  auto loadB = [&](half8* bf, int i){
    bf[0] = Bh8[base8 +             i*512];
    bf[1] = Bh8[base8 +   16384 +   i*512];
    bf[2] = Bh8[base8 + 2*16384 +   i*512];
    bf[3] = Bh8[base8 + 3*16384 +   i*512];
    bf[4] = Bl8[base8 +             i*512];
    bf[5] = Bl8[base8 +   16384 +   i*512];
    bf[6] = Bl8[base8 + 2*16384 +   i*512];
    bf[7] = Bl8[base8 + 3*16384 +   i*512];
  };

  // ================= CDE RK4 scan =================
  for (int t = 0; t < NSEG; ++t){
    // stage dX variants (readers are in phase B, after barrier 1)
    {
      int r = tid >> 5, i = tid & 31;
      const float* base = coeffs + (size_t)(bg + r)*(NSEG*128) + (size_t)t*128;
      float bb = base[32+i], cc = base[64+i], dd = base[96+i];
      dXT[0][i][r] = bb;
      dXT[1][i][r] = bb + cc + 0.75f*dd;
      float d4;
      if (t < NSEG-1) d4 = base[128+32+i];
      else            d4 = bb + 2.0f*cc + 3.0f*dd;
      dXT[2][i][r] = d4;
    }

    #pragma unroll 1
    for (int s = 0; s < 4; ++s){
      // prefetch first two W2 B-fragments (independent of this step's work)
      half8 b0[8], b1f[8];
      loadB(b0, 0);
      loadB(b1f, 1);

      // ---- Phase A: GEMM1: H = relu(Z @ W1 + b1), split-fp16 ----
      {
        half8 a1h[4], a1l[4];
        #pragma unroll
        for (int kt = 0; kt < 4; ++kt){
          a1h[kt] = *(const half8*)&Zs[ln16][kt*32 + q*8];
          a1l[kt] = *(const half8*)&Zl[ln16][kt*32 + q*8];
        }
        f32x4 u0 = sp4(b1v), u1 = sp4(0.0f), u2 = sp4(0.0f);
        #pragma unroll
        for (int kt = 0; kt < 4; ++kt){
          u0 = __builtin_amdgcn_mfma_f32_16x16x32_f16(a1h[kt], w1h[kt], u0, 0, 0, 0);
          u1 = __builtin_amdgcn_mfma_f32_16x16x32_f16(a1l[kt], w1h[kt], u1, 0, 0, 0);
          u2 = __builtin_amdgcn_mfma_f32_16x16x32_f16(a1h[kt], w1l[kt], u2, 0, 0, 0);
        }
        #pragma unroll
        for (int r = 0; r < 4; ++r){
          float hv = u0[r] + u1[r] + u2[r];
          hv = hv > 0.0f ? hv : 0.0f;
          _Float16 hi = (_Float16)hv;
          Hs[row4 + r][n0 + ln16] = hi;
          Hl[row4 + r][n0 + ln16] = (_Float16)(hv - (float)hi);
        }
      }
      __syncthreads();

      // ---- Phase B: GEMM2 + tanh + dX contraction, double-buffered B ----
      half8 a2h[4], a2l[4];
      #pragma unroll
      for (int kt = 0; kt < 4; ++kt){
        a2h[kt] = *(const half8*)&Hs[ln16][kt*32 + q*8];
        a2l[kt] = *(const half8*)&Hl[ln16][kt*32 + q*8];
      }
      const int v = (s == 0) ? 0 : ((s == 3) ? 2 : 1);
      f32x4 dz = sp4(0.0f);

      auto body = [&](const half8* bf, int i){
        float b2v = b2L[i*128 + n0 + ln16];
        f32x4 u0 = sp4(b2v), u1 = sp4(0.0f), u2 = sp4(0.0f);
        u0 = __builtin_amdgcn_mfma_f32_16x16x32_f16(a2h[0], bf[0], u0, 0, 0, 0);
        u1 = __builtin_amdgcn_mfma_f32_16x16x32_f16(a2l[0], bf[0], u1, 0, 0, 0);
        u2 = __builtin_amdgcn_mfma_f32_16x16x32_f16(a2h[0], bf[4], u2, 0, 0, 0);
        u0 = __builtin_amdgcn_mfma_f32_16x16x32_f16(a2h[1], bf[1], u0, 0, 0, 0);
        u1 = __builtin_amdgcn_mfma_f32_16x16x32_f16(a2l[1], bf[1], u1, 0, 0, 0);
        u2 = __builtin_amdgcn_mfma_f32_16x16x32_f16(a2h[1], bf[5], u2, 0, 0, 0);
        u0 = __builtin_amdgcn_mfma_f32_16x16x32_f16(a2h[2], bf[2], u0, 0, 0, 0);
        u1 = __builtin_amdgcn_mfma_f32_16x16x32_f16(a2l[2], bf[2], u1, 0, 0, 0);
        u2 = __builtin_amdgcn_mfma_f32_16x16x32_f16(a2h[2], bf[6], u2, 0, 0, 0);
        u0 = __builtin_amdgcn_mfma_f32_16x16x32_f16(a2h[3], bf[3], u0, 0, 0, 0);
        u1 = __builtin_amdgcn_mfma_f32_16x16x32_f16(a2l[3], bf[3], u1, 0, 0, 0);
        u2 = __builtin_amdgcn_mfma_f32_16x16x32_f16(a2h[3], bf[7], u2, 0, 0, 0);
        f32x4 dxv = *(const f32x4*)&dXT[v][i][row4];
        #pragma unroll
        for (int r = 0; r < 4; ++r)
          dz[r] = fmaf(fast_tanh(u0[r] + u1[r] + u2[r]), dxv[r], dz[r]);
      };

      for (int ii = 0; ii < 30; ii += 2){
        body(b0, ii);
        loadB(b0, ii + 2);
        body(b1f, ii + 1);
        loadB(b1f, ii + 3);
      }
      body(b0, 30);
      body(b1f, 31);

      // ---- in-register RK4 update + Zs/Zl write ----
      const float wk = (s == 3) ? 1.0f : 2.0f;
      #pragma unroll
      for (int k = 0; k < 4; ++k){
        float zan = (s == 0) ? dz[k] : za[k] + wk*dz[k];
        za[k] = zan;
        float zs;
        if (s == 3){ zb[k] += zan*(1.0f/6.0f); zs = zb[k]; }
        else if (s == 2) zs = zb[k] + dz[k];
        else             zs = zb[k] + 0.5f*dz[k];
        _Float16 hi = (_Float16)zs;
        Zs[row4 + k][n0 + ln16] = hi;
        Zl[row4 + k][n0 + ln16] = (_Float16)(zs - (float)hi);
      }
      __syncthreads();
    }
  }

  // ---- write final z back to zfb for readout ----
  #pragma unroll
  for (int k = 0; k < 4; ++k)
    zfb[row4 + k][n0 + ln16] = zb[k];
  __syncthreads();

  // ================= readout + evolve head (fp32) =================
  const int r = tid >> 5, c = tid & 31;
  float yb = 0.0f, yac = 0.0f;
  {
    float yv = b_ro[c];
    #pragma unroll 8
    for (int h = 0; h < 128; ++h)
      yv = fmaf(zfb[r][h], W_ro[h*32 + c], yv);
    ylds[r][c] = yv;
    yb = yv;
  }
  __syncthreads();

  for (int st = 0; st < 10; ++st){
    #pragma unroll 1
    for (int s = 0; s < 4; ++s){
      // tmp = tanh(ys @ We1 + be1) -> b2L (reused as [16][128])
      {
        int rr = tid >> 5, m0 = (tid & 31) * 4;
        f32x4 acc = *(const f32x4*)&be1[m0];
        #pragma unroll 4
        for (int i = 0; i < 32; ++i)
          acc += sp4(ylds[rr][i]) * (*(const f32x4*)&We1[i*128 + m0]);
        f32x4 tt;
        tt.x = fast_tanh(acc.x); tt.y = fast_tanh(acc.y);
        tt.z = fast_tanh(acc.z); tt.w = fast_tanh(acc.w);
        *(f32x4*)&b2L[rr*128 + m0] = tt;
      }
      __syncthreads();
      {
        float kv = be2[c];
        #pragma unroll 8
        for (int m = 0; m < 128; ++m)
          kv = fmaf(b2L[r*128 + m], We2[m*32 + c], kv);
        float ysn;
        if      (s == 0){ yac = kv;        ysn = yb + 0.25f*kv; }
        else if (s == 1){ yac += 2.0f*kv;  ysn = yb + 0.25f*kv; }
        else if (s == 2){ yac += 2.0f*kv;  ysn = yb + 0.5f*kv;  }
        else            { yac += kv;       yb += yac*(1.0f/12.0f); ysn = yb; }
        ylds[r][c] = ysn;
      }
      __syncthreads();
    }
  }
  out[(size_t)(bg + r)*32 + c] = yb;
}

extern "C" void kernel_launch(void* const* d_in, const int* in_sizes, int n_in,
                              void* d_out, int out_size, void* d_ws, size_t ws_size,
                              hipStream_t stream){
  const float* coeffs = (const float*)d_in[0];
  const float* W_init = (const float*)d_in[1];
  const float* b_init = (const float*)d_in[2];
  const float* W1     = (const float*)d_in[3];
  const float* b1     = (const float*)d_in[4];
  const float* W2     = (const float*)d_in[5];
  const float* b2     = (const float*)d_in[6];
  const float* W_ro   = (const float*)d_in[7];
  const float* b_ro   = (const float*)d_in[8];
  const float* We1    = (const float*)d_in[9];
  const float* be1    = (const float*)d_in[10];
  const float* We2    = (const float*)d_in[11];
  const float* be2    = (const float*)d_in[12];
  _Float16* ws        = (_Float16*)d_ws;

  prep_kernel<<<2128, 256, 0, stream>>>(W1, W2, b2, ws);
  cde_kernel<<<128, 512, 0, stream>>>(coeffs, W_init, b_init, b1, W_ro, b_ro,
                                      We1, be1, We2, be2, ws, (float*)d_out);
}

// Round 6
// 3937.961 us; speedup vs baseline: 2.2022x; 1.8386x over previous
//
#include <hip/hip_runtime.h>

#define NSEG 63

typedef float    f32x4  __attribute__((ext_vector_type(4)));
typedef _Float16 half8  __attribute__((ext_vector_type(8)));
typedef _Float16 half4v __attribute__((ext_vector_type(4)));

#define W2_ELEMS 524288
#define W1_ELEMS 16384
#define W1H_OFF (2*W2_ELEMS)
#define W1L_OFF (W1H_OFF + W1_ELEMS)
#define B2_OFF  (W1L_OFF + W1_ELEMS)

__device__ __forceinline__ float fast_tanh(float x){
  float e = __builtin_amdgcn_exp2f(x * 2.885390081777927f); // 2*log2(e)
  float r = __builtin_amdgcn_rcpf(e + 1.0f);
  return fmaf(-2.0f, r, 1.0f);
}

__device__ __forceinline__ f32x4 sp4(float v){ f32x4 o = {v,v,v,v}; return o; }

__global__ __launch_bounds__(256) void prep_kernel(const float* __restrict__ W1,
                                                   const float* __restrict__ W2,
                                                   const float* __restrict__ b2,
                                                   _Float16* __restrict__ ws){
  int idx = blockIdx.x*256 + threadIdx.x;
  if (idx < W2_ELEMS){
    int m = idx >> 12, col = idx & 4095;       // W2[m][col], col = h*32+i
    int h = col >> 5,  i = col & 31;
    int kt = m >> 5,   kk = m & 31;
    int np = i*128 + h;
    float w = W2[idx];
    _Float16 hi = (_Float16)w;                 // fp16-hi only (lo plane dropped)
    int pos = (kt*4096 + np)*32 + kk;
    ws[pos] = hi;
  } else if (idx < W2_ELEMS + W1_ELEMS){
    int j = idx - W2_ELEMS;
    int m = j >> 7, n = j & 127;               // W1[m][n]
    float w = W1[j];
    _Float16 hi = (_Float16)w;
    _Float16 lo = (_Float16)(w - (float)hi);
    int pos = ((m>>5)*128 + n)*32 + (m&31);
    ws[W1H_OFF + pos] = hi;
    ws[W1L_OFF + pos] = lo;
  } else if (idx < W2_ELEMS + W1_ELEMS + 4096){
    int j = idx - (W2_ELEMS + W1_ELEMS);       // b2[h*32+i]
    float* b2p = (float*)(ws + B2_OFF);
    b2p[(j & 31)*128 + (j >> 5)] = b2[j];
  }
}

// 128 WGs x 512 threads x 16 rows. 1 M-tile per wave, register z-state,
// 2 barriers/substep, register double-buffered W2 B-fragments (hi plane only).
// amdgpu_waves_per_eu(2,2): pin occupancy so allocator can use up to 256 VGPRs.
__global__ __launch_bounds__(512)
__attribute__((amdgpu_waves_per_eu(2, 2)))
void cde_kernel(
    const float* __restrict__ coeffs,
    const float* __restrict__ W_init, const float* __restrict__ b_init,
    const float* __restrict__ b1,
    const float* __restrict__ W_ro,  const float* __restrict__ b_ro,
    const float* __restrict__ We1,   const float* __restrict__ be1,
    const float* __restrict__ We2,   const float* __restrict__ be2,
    const _Float16* __restrict__ wsw,
    float* __restrict__ out)
{
  __shared__ __align__(16) _Float16 Zs[16][136];  // stage-z hi (A of GEMM1)
  __shared__ __align__(16) _Float16 Zl[16][136];  // stage-z lo
  __shared__ __align__(16) _Float16 Hs[16][136];  // H hi (A of GEMM2)
  __shared__ __align__(16) _Float16 Hl[16][136];  // H lo
  __shared__ __align__(16) float dXT[3][32][16];  // dX variants [var][i][row]
  __shared__ __align__(16) float zfb[16][128];    // z0 init + final readout
  __shared__ __align__(16) float ylds[16][32];    // evolve stage y
  __shared__ __align__(16) float b2L[4096];       // permuted b2; reused as evolve tmp

  const int tid  = threadIdx.x;
  const int wave = tid >> 6;          // 0..7
  const int lane = tid & 63;
  const int q    = lane >> 4;
  const int ln16 = lane & 15;
  const int row4 = q * 4;
  const int bg   = blockIdx.x * 16;
  const int n0   = wave * 16;

  // ---- stage b2p into LDS ----
  {
    const float* b2p = (const float*)(wsw + B2_OFF);
    #pragma unroll
    for (int j = 0; j < 8; ++j) b2L[tid + j*512] = b2p[tid + j*512];
  }
  // ---- stage X0 = a[:,0] into dXT[0][i][r] ----
  {
    int r = tid >> 5, i = tid & 31;
    dXT[0][i][r] = coeffs[(size_t)(bg + r)*(NSEG*128) + i];
  }
  __syncthreads();

  // ---- z0 = X0 @ W_init + b_init (fp32) -> zfb + Zs/Zl ----
  {
    int r = tid >> 5, h0 = (tid & 31) * 4;
    f32x4 acc = *(const f32x4*)&b_init[h0];
    #pragma unroll 8
    for (int i = 0; i < 32; ++i)
      acc += sp4(dXT[0][i][r]) * (*(const f32x4*)&W_init[i*128 + h0]);
    *(f32x4*)&zfb[r][h0] = acc;
    half4v zh, zl;
    #pragma unroll
    for (int k = 0; k < 4; ++k){
      _Float16 hi = (_Float16)acc[k];
      zh[k] = hi; zl[k] = (_Float16)(acc[k] - (float)hi);
    }
    *(half4v*)&Zs[r][h0] = zh;
    *(half4v*)&Zl[r][h0] = zl;
  }

  // per-wave W1 fragments (persist in regs)
  half8 w1h[4], w1l[4];
  {
    const half8* W1h8 = (const half8*)(wsw + W1H_OFF);
    const half8* W1l8 = (const half8*)(wsw + W1L_OFF);
    #pragma unroll
    for (int kt = 0; kt < 4; ++kt){
      int fi = (kt*128 + n0 + ln16)*4 + q;
      w1h[kt] = W1h8[fi];
      w1l[kt] = W1l8[fi];
    }
  }
  const float b1v = b1[n0 + ln16];
  const half8* Bh8 = (const half8*)wsw;
  const int base8 = (n0 + ln16)*4 + q;
  __syncthreads();

  // ---- register z-state for owned fragment ----
  f32x4 zb, za = sp4(0.0f);
  #pragma unroll
  for (int k = 0; k < 4; ++k)
    zb[k] = zfb[row4 + k][n0 + ln16];

  // B-fragment loader: 4 hi-plane frags (kt 0..3)
  auto loadB = [&](half8* bf, int i){
    bf[0] = Bh8[base8 +             i*512];
    bf[1] = Bh8[base8 +   16384 +   i*512];
    bf[2] = Bh8[base8 + 2*16384 +   i*512];
    bf[3] = Bh8[base8 + 3*16384 +   i*512];
  };

  // ================= CDE RK4 scan =================
  for (int t = 0; t < NSEG; ++t){
    // stage dX variants (readers are in phase B, after barrier 1)
    {
      int r = tid >> 5, i = tid & 31;
      const float* base = coeffs + (size_t)(bg + r)*(NSEG*128) + (size_t)t*128;
      float bb = base[32+i], cc = base[64+i], dd = base[96+i];
      dXT[0][i][r] = bb;
      dXT[1][i][r] = bb + cc + 0.75f*dd;
      float d4;
      if (t < NSEG-1) d4 = base[128+32+i];
      else            d4 = bb + 2.0f*cc + 3.0f*dd;
      dXT[2][i][r] = d4;
    }

    #pragma unroll 1
    for (int s = 0; s < 4; ++s){
      // prefetch first two W2 B-fragments (independent of this step's work)
      half8 b0[4], b1f[4];
      loadB(b0, 0);
      loadB(b1f, 1);

      // ---- Phase A: GEMM1: H = relu(Z @ W1 + b1), split-fp16 ----
      {
        half8 a1h[4], a1l[4];
        #pragma unroll
        for (int kt = 0; kt < 4; ++kt){
          a1h[kt] = *(const half8*)&Zs[ln16][kt*32 + q*8];
          a1l[kt] = *(const half8*)&Zl[ln16][kt*32 + q*8];
        }
        f32x4 u0 = sp4(b1v), u1 = sp4(0.0f), u2 = sp4(0.0f);
        #pragma unroll
        for (int kt = 0; kt < 4; ++kt){
          u0 = __builtin_amdgcn_mfma_f32_16x16x32_f16(a1h[kt], w1h[kt], u0, 0, 0, 0);
          u1 = __builtin_amdgcn_mfma_f32_16x16x32_f16(a1l[kt], w1h[kt], u1, 0, 0, 0);
          u2 = __builtin_amdgcn_mfma_f32_16x16x32_f16(a1h[kt], w1l[kt], u2, 0, 0, 0);
        }
        #pragma unroll
        for (int r = 0; r < 4; ++r){
          float hv = u0[r] + u1[r] + u2[r];
          hv = hv > 0.0f ? hv : 0.0f;
          _Float16 hi = (_Float16)hv;
          Hs[row4 + r][n0 + ln16] = hi;
          Hl[row4 + r][n0 + ln16] = (_Float16)(hv - (float)hi);
        }
      }
      __syncthreads();

      // ---- Phase B: GEMM2 + tanh + dX contraction, double-buffered B ----
      half8 a2h[4], a2l[4];
      #pragma unroll
      for (int kt = 0; kt < 4; ++kt){
        a2h[kt] = *(const half8*)&Hs[ln16][kt*32 + q*8];
        a2l[kt] = *(const half8*)&Hl[ln16][kt*32 + q*8];
      }
      const int v = (s == 0) ? 0 : ((s == 3) ? 2 : 1);
      f32x4 dz = sp4(0.0f);

      auto body = [&](const half8* bf, int i){
        float b2v = b2L[i*128 + n0 + ln16];
        f32x4 u0 = sp4(b2v), u1 = sp4(0.0f);
        u0 = __builtin_amdgcn_mfma_f32_16x16x32_f16(a2h[0], bf[0], u0, 0, 0, 0);
        u1 = __builtin_amdgcn_mfma_f32_16x16x32_f16(a2l[0], bf[0], u1, 0, 0, 0);
        u0 = __builtin_amdgcn_mfma_f32_16x16x32_f16(a2h[1], bf[1], u0, 0, 0, 0);
        u1 = __builtin_amdgcn_mfma_f32_16x16x32_f16(a2l[1], bf[1], u1, 0, 0, 0);
        u0 = __builtin_amdgcn_mfma_f32_16x16x32_f16(a2h[2], bf[2], u0, 0, 0, 0);
        u1 = __builtin_amdgcn_mfma_f32_16x16x32_f16(a2l[2], bf[2], u1, 0, 0, 0);
        u0 = __builtin_amdgcn_mfma_f32_16x16x32_f16(a2h[3], bf[3], u0, 0, 0, 0);
        u1 = __builtin_amdgcn_mfma_f32_16x16x32_f16(a2l[3], bf[3], u1, 0, 0, 0);
        f32x4 dxv = *(const f32x4*)&dXT[v][i][row4];
        #pragma unroll
        for (int r = 0; r < 4; ++r)
          dz[r] = fmaf(fast_tanh(u0[r] + u1[r]), dxv[r], dz[r]);
      };

      for (int ii = 0; ii < 30; ii += 2){
        body(b0, ii);
        loadB(b0, ii + 2);
        body(b1f, ii + 1);
        loadB(b1f, ii + 3);
      }
      body(b0, 30);
      body(b1f, 31);

      // ---- in-register RK4 update + Zs/Zl write ----
      const float wk = (s == 3) ? 1.0f : 2.0f;
      #pragma unroll
      for (int k = 0; k < 4; ++k){
        float zan = (s == 0) ? dz[k] : za[k] + wk*dz[k];
        za[k] = zan;
        float zs;
        if (s == 3){ zb[k] += zan*(1.0f/6.0f); zs = zb[k]; }
        else if (s == 2) zs = zb[k] + dz[k];
        else             zs = zb[k] + 0.5f*dz[k];
        _Float16 hi = (_Float16)zs;
        Zs[row4 + k][n0 + ln16] = hi;
        Zl[row4 + k][n0 + ln16] = (_Float16)(zs - (float)hi);
      }
      __syncthreads();
    }
  }

  // ---- write final z back to zfb for readout ----
  #pragma unroll
  for (int k = 0; k < 4; ++k)
    zfb[row4 + k][n0 + ln16] = zb[k];
  __syncthreads();

  // ================= readout + evolve head (fp32) =================
  const int r = tid >> 5, c = tid & 31;
  float yb = 0.0f, yac = 0.0f;
  {
    float yv = b_ro[c];
    #pragma unroll 8
    for (int h = 0; h < 128; ++h)
      yv = fmaf(zfb[r][h], W_ro[h*32 + c], yv);
    ylds[r][c] = yv;
    yb = yv;
  }
  __syncthreads();

  for (int st = 0; st < 10; ++st){
    #pragma unroll 1
    for (int s = 0; s < 4; ++s){
      // tmp = tanh(ys @ We1 + be1) -> b2L (reused as [16][128])
      {
        int rr = tid >> 5, m0 = (tid & 31) * 4;
        f32x4 acc = *(const f32x4*)&be1[m0];
        #pragma unroll 4
        for (int i = 0; i < 32; ++i)
          acc += sp4(ylds[rr][i]) * (*(const f32x4*)&We1[i*128 + m0]);
        f32x4 tt;
        tt.x = fast_tanh(acc.x); tt.y = fast_tanh(acc.y);
        tt.z = fast_tanh(acc.z); tt.w = fast_tanh(acc.w);
        *(f32x4*)&b2L[rr*128 + m0] = tt;
      }
      __syncthreads();
      {
        float kv = be2[c];
        #pragma unroll 8
        for (int m = 0; m < 128; ++m)
          kv = fmaf(b2L[r*128 + m], We2[m*32 + c], kv);
        float ysn;
        if      (s == 0){ yac = kv;        ysn = yb + 0.25f*kv; }
        else if (s == 1){ yac += 2.0f*kv;  ysn = yb + 0.25f*kv; }
        else if (s == 2){ yac += 2.0f*kv;  ysn = yb + 0.5f*kv;  }
        else            { yac += kv;       yb += yac*(1.0f/12.0f); ysn = yb; }
        ylds[r][c] = ysn;
      }
      __syncthreads();
    }
  }
  out[(size_t)(bg + r)*32 + c] = yb;
}

extern "C" void kernel_launch(void* const* d_in, const int* in_sizes, int n_in,
                              void* d_out, int out_size, void* d_ws, size_t ws_size,
                              hipStream_t stream){
  const float* coeffs = (const float*)d_in[0];
  const float* W_init = (const float*)d_in[1];
  const float* b_init = (const float*)d_in[2];
  const float* W1     = (const float*)d_in[3];
  const float* b1     = (const float*)d_in[4];
  const float* W2     = (const float*)d_in[5];
  const float* b2     = (const float*)d_in[6];
  const float* W_ro   = (const float*)d_in[7];
  const float* b_ro   = (const float*)d_in[8];
  const float* We1    = (const float*)d_in[9];
  const float* be1    = (const float*)d_in[10];
  const float* We2    = (const float*)d_in[11];
  const float* be2    = (const float*)d_in[12];
  _Float16* ws        = (_Float16*)d_ws;

  prep_kernel<<<2128, 256, 0, stream>>>(W1, W2, b2, ws);
  cde_kernel<<<128, 512, 0, stream>>>(coeffs, W_init, b_init, b1, W_ro, b_ro,
                                      We1, be1, We2, be2, ws, (float*)d_out);
}